// Round 13
// baseline (1739.725 us; speedup 1.0000x reference)
//
#include <hip/hip_runtime.h>
#include <math.h>

#define TT 2048
#define RB 16      // batch rows per block (MFMA M)
#define HH 64

typedef __fp16 f16x8 __attribute__((ext_vector_type(8)));   // clang MFMA f16 operand type
typedef float  f32x4 __attribute__((ext_vector_type(4)));

#if __has_builtin(__builtin_amdgcn_rcpf)
__device__ __forceinline__ float fast_rcp(float v) { return __builtin_amdgcn_rcpf(v); }
#else
__device__ __forceinline__ float fast_rcp(float v) { return 1.0f / v; }
#endif
#if __has_builtin(__builtin_amdgcn_rsqf)
__device__ __forceinline__ float fast_rsq(float v) { return __builtin_amdgcn_rsqf(v); }
#else
__device__ __forceinline__ float fast_rsq(float v) { return rsqrtf(v); }
#endif

__device__ __forceinline__ float tanh_fast(float v) {
    float e = __expf(2.0f * v);
    return fmaf(-2.0f, fast_rcp(e + 1.0f), 1.0f);
}
__device__ __forceinline__ float sigmoid_fast(float v) {
    return fast_rcp(1.0f + __expf(-v));
}
// s*(1-s) with s = tanh(z)
__device__ __forceinline__ float dtanh_of(float z) {
    float s = tanh_fast(z);
    return s - s * s;
}

__device__ __forceinline__ f32x4 mfma16(f16x8 a, f16x8 b, f32x4 c) {
    return __builtin_amdgcn_mfma_f32_16x16x32_f16(a, b, c, 0, 0, 0);
}

// 16x64 f16 tile in LDS: row stride 128B, 16B chunks xor-swizzled by row&7
__device__ __forceinline__ int tile_addr(int row, int col) {
    return row * 128 + (((col >> 3) ^ (row & 7)) << 4) + ((col & 7) << 1);
}
// A-frag read: lane holds A[m][k], k = c8*8..c8*8+7 (16 contiguous swizzled bytes)
__device__ __forceinline__ int frag_addr(int m, int c8) {
    return m * 128 + ((c8 ^ (m & 7)) << 4);
}

// B-frag: lane holds B[k][n] = W[n][k], k = k0..k0+7 (contiguous in row-major W)
__device__ __forceinline__ f16x8 load_bfrag(const float* __restrict__ W, int ld, int row, int k0) {
    f16x8 r;
#pragma unroll
    for (int j = 0; j < 8; ++j) r[j] = (__fp16)W[row * ld + k0 + j];
    return r;
}

union F8I4 { f16x8 f; int i[4]; };
__device__ __forceinline__ void pin_frag(f16x8& v) {
    F8I4 u; u.f = v;
    asm volatile("" : "+v"(u.i[0]), "+v"(u.i[1]), "+v"(u.i[2]), "+v"(u.i[3]));
    v = u.f;
}

__device__ __forceinline__ void xscalars(float2 xv, float& amp, float& ct, float& st) {
    float r2 = xv.x * xv.x + xv.y * xv.y;
    float rq = fast_rsq(r2);
    bool ok = r2 > 0.f;
    amp = ok ? r2 * rq : 0.f;
    ct  = ok ? xv.x * rq : 1.f;   // cos(atan2(q,i)); atan2(0,0)=0 -> cos=1
    st  = ok ? xv.y * rq : 0.f;
}

__global__ __launch_bounds__(256, 1)
void pgjanet_kernel(const float* __restrict__ x,
                    const float* __restrict__ h0,
                    const float* __restrict__ Wa,  const float* __restrict__ ba,
                    const float* __restrict__ Wp1, const float* __restrict__ bp1,
                    const float* __restrict__ Wp2, const float* __restrict__ bp2,
                    const float* __restrict__ Wf,  const float* __restrict__ bf,
                    const float* __restrict__ Wg,  const float* __restrict__ bg,
                    const float* __restrict__ Wo,  const float* __restrict__ bo,
                    float* __restrict__ out)
{
    const int blk  = blockIdx.x;
    const int tid  = threadIdx.x;
    const int lane = tid & 63;
    const int w    = __builtin_amdgcn_readfirstlane(tid >> 6);  // n-slice 0..3
    const int q    = lane >> 4;        // quad
    const int n    = lane & 15;        // col within slice / A-frag m
    const int colg = 16 * w + n;       // global output col

    __shared__ __align__(16) char smem[4096];   // hbuf @0 (2KB), ubuf @2048 (2KB)

    // loop-invariant LDS addresses
    int wrA[4], rdA[2];
#pragma unroll
    for (int r = 0; r < 4; ++r) wrA[r] = tile_addr(q * 4 + r, colg);
    rdA[0] = frag_addr(n, q);        // k-chunk 0: k = q*8..q*8+7
    rdA[1] = frag_addr(n, 4 + q);    // k-chunk 1: k = 32+q*8..

    // ---- weights as B-frags (per wave: its 16-col n-slice of every matrix) ----
    f16x8 Ba[2], Bp1[2], Bp2[2], Bfh[2], Bgh[2], Bfu[2], Bgu[2], Bwo[2];
#pragma unroll
    for (int c = 0; c < 2; ++c) {
        const int k0 = 32 * c + q * 8;
        Ba[c]  = load_bfrag(Wa,  HH + 1, colg, k0);
        Bp1[c] = load_bfrag(Wp1, HH + 1, colg, k0);
        Bp2[c] = load_bfrag(Wp2, HH + 1, colg, k0);
        Bfh[c] = load_bfrag(Wf,  2 * HH, colg, k0);
        Bgh[c] = load_bfrag(Wg,  2 * HH, colg, k0);
        Bfu[c] = load_bfrag(Wf,  2 * HH, colg, HH + k0);
        Bgu[c] = load_bfrag(Wg,  2 * HH, colg, HH + k0);
        Bwo[c] = load_bfrag(Wo,  HH, (n < 2) ? n : 1, k0);   // clamped; n>=2 unused
    }
#pragma unroll
    for (int c = 0; c < 2; ++c) {
        pin_frag(Ba[c]);  pin_frag(Bp1[c]); pin_frag(Bp2[c]);
        pin_frag(Bfh[c]); pin_frag(Bgh[c]); pin_frag(Bfu[c]); pin_frag(Bgu[c]);
        pin_frag(Bwo[c]);
    }

    const float waH = Wa [colg * (HH + 1) + HH];
    const float w1H = Wp1[colg * (HH + 1) + HH];
    const float w2H = Wp2[colg * (HH + 1) + HH];
    const float ba_r = ba[colg], b1_r = bp1[colg], b2_r = bp2[colg];
    const float bf_r = bf[colg], bg_r = bg[colg];
    const float bo_n = (n < 2) ? bo[n] : 0.f;

    // ---- h0: C-layout slice + initial A-frags via LDS transpose ----
    float hC[4];
#pragma unroll
    for (int r = 0; r < 4; ++r)
        hC[r] = h0[(size_t)(RB * blk + q * 4 + r) * HH + colg];
#pragma unroll
    for (int r = 0; r < 4; ++r)
        *(__fp16*)(smem + wrA[r]) = (__fp16)hC[r];
    __syncthreads();
    f16x8 hA0 = *(const f16x8*)(smem + rdA[0]);
    f16x8 hA1 = *(const f16x8*)(smem + rdA[1]);

    // ---- x row pointers + t=0 scalars (lane needs rows q*4+r) ----
    const float2* xr[4];
#pragma unroll
    for (int r = 0; r < 4; ++r)
        xr[r] = (const float2*)(x + (size_t)(RB * blk + q * 4 + r) * TT * 2);
    float amp[4], ct[4], st[4];
#pragma unroll
    for (int r = 0; r < 4; ++r) xscalars(xr[r][0], amp[r], ct[r], st[r]);

    // ---- y store pointers (wave0, n<2 lanes) ----
    float* yp[4];
#pragma unroll
    for (int r = 0; r < 4; ++r)
        yp[r] = out + (size_t)(RB * blk + q * 4 + r) * TT * 2 + n;

    for (int t = 0; t < TT; ++t) {
        // y_{t-1} = h_t @ Wo.T + bo (hA currently holds h_t)
        if (w == 0 && t > 0) {
            f32x4 zy = {0.f, 0.f, 0.f, 0.f};
            f32x4 yv = mfma16(hA1, Bwo[1], mfma16(hA0, Bwo[0], zy));
            if (n < 2) {
#pragma unroll
                for (int r = 0; r < 4; ++r) { yp[r][0] = yv[r] + bo_n; yp[r] += 2; }
            }
        }

        // prefetch x[t+1]
        const int tn = (t + 1 < TT) ? (t + 1) : (TT - 1);
        float2 xnv[4];
#pragma unroll
        for (int r = 0; r < 4; ++r) xnv[r] = xr[r][tn];

        // ---- phase A: 10 MFMAs (bias in C-init) ----
        f32x4 accA = {ba_r, ba_r, ba_r, ba_r};
        f32x4 acc1 = {b1_r, b1_r, b1_r, b1_r};
        f32x4 acc2 = {b2_r, b2_r, b2_r, b2_r};
        f32x4 accF = {bf_r, bf_r, bf_r, bf_r};
        f32x4 accG = {bg_r, bg_r, bg_r, bg_r};
        accA = mfma16(hA1, Ba[1],  mfma16(hA0, Ba[0],  accA));
        acc1 = mfma16(hA1, Bp1[1], mfma16(hA0, Bp1[0], acc1));
        acc2 = mfma16(hA1, Bp2[1], mfma16(hA0, Bp2[0], acc2));
        accF = mfma16(hA1, Bfh[1], mfma16(hA0, Bfh[0], accF));
        accG = mfma16(hA1, Bgh[1], mfma16(hA0, Bgh[0], accG));

        // x-column + activations -> u, write to ubuf
#pragma unroll
        for (int r = 0; r < 4; ++r) {
            float sa = dtanh_of(accA[r] + amp[r] * waH);
            float s1 = dtanh_of(acc1[r] + ct[r]  * w1H);
            float s2 = dtanh_of(acc2[r] + st[r]  * w2H);
            float u  = sa * s1 * s2;
            *(__fp16*)(smem + 2048 + wrA[r]) = (__fp16)u;
        }
        __syncthreads();   // barrier 1: u transpose visible

        f16x8 uA0 = *(const f16x8*)(smem + 2048 + rdA[0]);
        f16x8 uA1 = *(const f16x8*)(smem + 2048 + rdA[1]);
        accF = mfma16(uA1, Bfu[1], mfma16(uA0, Bfu[0], accF));
        accG = mfma16(uA1, Bgu[1], mfma16(uA0, Bgu[0], accG));

        // next step's x scalars (off critical path; amp/ct/st already consumed)
#pragma unroll
        for (int r = 0; r < 4; ++r) xscalars(xnv[r], amp[r], ct[r], st[r]);

        // f/g -> h_new; write h transpose
#pragma unroll
        for (int r = 0; r < 4; ++r) {
            float f = sigmoid_fast(accF[r]);
            float g = tanh_fast(accG[r]);
            hC[r] = fmaf(f, hC[r] - g, g);     // f*h + (1-f)*g
            *(__fp16*)(smem + wrA[r]) = (__fp16)hC[r];
        }
        __syncthreads();   // barrier 2: h transpose visible

        hA0 = *(const f16x8*)(smem + rdA[0]);
        hA1 = *(const f16x8*)(smem + rdA[1]);
    }

    // tail: y_{TT-1} from final h
    if (w == 0) {
        f32x4 zy = {0.f, 0.f, 0.f, 0.f};
        f32x4 yv = mfma16(hA1, Bwo[1], mfma16(hA0, Bwo[0], zy));
        if (n < 2) {
#pragma unroll
            for (int r = 0; r < 4; ++r) yp[r][0] = yv[r] + bo_n;
        }
    }
}

extern "C" void kernel_launch(void* const* d_in, const int* in_sizes, int n_in,
                              void* d_out, int out_size, void* d_ws, size_t ws_size,
                              hipStream_t stream) {
    const float* x   = (const float*)d_in[0];
    const float* h0  = (const float*)d_in[1];
    const float* Wa  = (const float*)d_in[2];
    const float* ba  = (const float*)d_in[3];
    const float* Wp1 = (const float*)d_in[4];
    const float* bp1 = (const float*)d_in[5];
    const float* Wp2 = (const float*)d_in[6];
    const float* bp2 = (const float*)d_in[7];
    const float* Wf  = (const float*)d_in[8];
    const float* bf  = (const float*)d_in[9];
    const float* Wg  = (const float*)d_in[10];
    const float* bg  = (const float*)d_in[11];
    const float* Wo  = (const float*)d_in[12];
    const float* bo  = (const float*)d_in[13];
    float* out = (float*)d_out;

    pgjanet_kernel<<<dim3(256 / RB), dim3(256), 0, stream>>>(
        x, h0, Wa, ba, Wp1, bp1, Wp2, bp2, Wf, bf, Wg, bg, Wo, bo, out);
}